// Round 11
// baseline (305.994 us; speedup 1.0000x reference)
//
#include <hip/hip_runtime.h>
#include <math.h>

#define PCK_STRIDE 416
#define N_SAMPLES  32768
#define FFT_M      16384        // complex FFT size (real packing)
#define B_EVENTS   128
#define NT         1024
#define PI_F 3.14159265358979323846f
#define RT2H 0.70710678118654752f   // sqrt(2)/2

// LDS padded mapping: +4 floats per 32-block (keeps 8-blocks contiguous and
// 16B-aligned; all r4/r8 accesses <=2-way bank aliasing).
#define MAP(i) ((i) + (((i) >> 5) << 2))
#define LDS_N  18432            // 16384 + 2048 pad
// LDS floats: re/im (2*18432) + filt 16 + s_res 1024 + s_amp 128 + s_rw 8
#define LDS_TOTAL (2 * LDS_N + 16 + 1024 + 128 + 8)   // 38040 floats = 152160 B < 160 KB

__device__ inline float filt_at(const float* __restrict__ f, int k) {
    if (k >= FFT_M) return 0.0f;
    float c = ((float)k + 0.5f) * (1.0f / 1024.0f) - 0.5f;
    c = fminf(fmaxf(c, 0.0f), 15.0f);
    int i0 = (int)floorf(c);
    int i1 = min(i0 + 1, 15);
    float w = c - (float)i0;
    return f[i0] * (1.0f - w) + f[i1] * w;
}

// ---------------- radix-4 LDS stages ----------------
// unroll 1: fits the 64-VGPR budget the allocator pins for 1024-thread
// blocks (R6/R8/R9 evidence). 16 waves/CU supply latency hiding.
template<int L>
__device__ inline void r4_dif_stage(float* re, float* im, int tid) {
    constexpr int q = L >> 2;
    constexpr float ang = -6.28318530717958647692f / (float)L;
    #pragma unroll 1
    for (int s = 0; s < (FFT_M / 4) / NT; ++s) {
        int m = tid + s * NT;
        int t = m & (q - 1);
        int i0 = ((m & ~(q - 1)) << 2) | t;
        int ia = MAP(i0), ib = MAP(i0 + q), ic = MAP(i0 + 2 * q), id = MAP(i0 + 3 * q);
        float ar = re[ia], ai = im[ia];
        float br = re[ib], bi = im[ib];
        float cr = re[ic], ci = im[ic];
        float dr = re[id], di = im[id];
        float s1, c1; __sincosf(ang * (float)t, &s1, &c1);
        float c2 = c1 * c1 - s1 * s1, s2 = 2.0f * c1 * s1;
        float c3 = c2 * c1 - s2 * s1, s3 = c2 * s1 + s2 * c1;
        float s0r = ar + cr, s0i = ai + ci;
        float t1r = br + dr, t1i = bi + di;
        float d0r = ar - cr, d0i = ai - ci;
        float d1r = br - dr, d1i = bi - di;
        re[ia] = s0r + t1r; im[ia] = s0i + t1i;
        float er = s0r - t1r, ei = s0i - t1i;
        re[ib] = er * c2 - ei * s2; im[ib] = er * s2 + ei * c2;
        float fr = d0r + d1i, fi = d0i - d1r;   // (a-c) - i(b-d)
        re[ic] = fr * c1 - fi * s1; im[ic] = fr * s1 + fi * c1;
        float gr = d0r - d1i, gi = d0i + d1r;   // (a-c) + i(b-d)
        re[id] = gr * c3 - gi * s3; im[id] = gr * s3 + gi * c3;
    }
    __syncthreads();
}

template<int L>
__device__ inline void r4_dit_stage(float* re, float* im, int tid) {
    constexpr int q = L >> 2;
    constexpr float ang = 6.28318530717958647692f / (float)L;
    #pragma unroll 1
    for (int s = 0; s < (FFT_M / 4) / NT; ++s) {
        int m = tid + s * NT;
        int t = m & (q - 1);
        int i0 = ((m & ~(q - 1)) << 2) | t;
        int ia = MAP(i0), ib = MAP(i0 + q), ic = MAP(i0 + 2 * q), id = MAP(i0 + 3 * q);
        float ar = re[ia], ai = im[ia];
        float br = re[ib], bi = im[ib];
        float cr = re[ic], ci = im[ic];
        float dr = re[id], di = im[id];
        float s1, c1; __sincosf(ang * (float)t, &s1, &c1);
        float c2 = c1 * c1 - s1 * s1, s2 = 2.0f * c1 * s1;
        float tbr = br * c2 - bi * s2, tbi = br * s2 + bi * c2;
        float tdr = dr * c2 - di * s2, tdi = dr * s2 + di * c2;
        float B0r = ar + tbr, B0i = ai + tbi;
        float B1r = ar - tbr, B1i = ai - tbi;
        float B2r = cr + tdr, B2i = ci + tdi;
        float B3r = cr - tdr, B3i = ci - tdi;
        float t0r = B2r * c1 - B2i * s1, t0i = B2r * s1 + B2i * c1;
        float t1r = -B3r * s1 - B3i * c1, t1i = B3r * c1 - B3i * s1;  // B3*(i*w1)
        re[ia] = B0r + t0r; im[ia] = B0i + t0i;
        re[ib] = B1r + t1r; im[ib] = B1i + t1i;
        re[ic] = B0r - t0r; im[ic] = B0i - t0i;
        re[id] = B1r - t1r; im[id] = B1i - t1i;
    }
    __syncthreads();
}

// ---------------- K: 16384-pt FFT filter + fused prep + fused assemble ----------------
__global__ __launch_bounds__(NT)
void fft_filter_kernel(
    const float* __restrict__ noise, const float* __restrict__ packed,
    const float* __restrict__ gamp, const float* __restrict__ oamp,
    const float* __restrict__ freqs, float* __restrict__ out)
{
    extern __shared__ float smem[];
    float* re = smem;
    float* im = smem + LDS_N;
    float* filt   = smem + 2 * LDS_N;       // 16
    float* s_resd = filt + 16;              // [8][128] pre-scaled by osc_amp*mask
    float* s_amp  = s_resd + 1024;          // 128 gated-amp frames (2x-1)
    float* s_rw   = s_amp + 128;            // 8 radians
    const int b = blockIdx.x;
    const int tid = threadIdx.x;
    const float g = gamp[0];

    // --- load + fused r2 DIF (half=8192) ---
    const float2* nz = (const float2*)(noise + (size_t)b * N_SAMPLES);
    #pragma unroll 1
    for (int s = 0; s < 8192 / NT; ++s) {
        int j = tid + s * NT;
        float2 v0 = nz[j];
        float2 v1 = nz[j + 8192];
        float ur = v0.x * g, ui = v0.y * g;
        float wr = v1.x * g, wi = v1.y * g;
        float s1, c1; __sincosf((-PI_F / 8192.0f) * (float)j, &s1, &c1);
        int a0 = MAP(j), a1 = MAP(j + 8192);
        re[a0] = ur + wr; im[a0] = ui + wi;
        float dr = ur - wr, di = ui - wi;
        re[a1] = dr * c1 - di * s1;
        im[a1] = dr * s1 + di * c1;
    }
    if (tid >= 64 && tid < 80) filt[tid - 64] = packed[b * PCK_STRIDE + 400 + (tid - 64)];

    // --- fused prep on wave 0 (shuffle-only): softmax-f0, radians, decay scan -> LDS ---
    if (tid < 64) {
        const float* row = packed + b * PCK_STRIDE;
        float n0 = row[tid], n1 = row[tid + 64];
        float fq0 = freqs[tid], fq1 = freqs[tid + 64];
        float mx = fmaxf(n0, n1);
        #pragma unroll
        for (int off = 32; off >= 1; off >>= 1) mx = fmaxf(mx, __shfl_xor(mx, off));
        float e0 = __expf(n0 - mx), e1 = __expf(n1 - mx);
        float den = e0 + e1, num = e0 * fq0 + e1 * fq1;
        #pragma unroll
        for (int off = 32; off >= 1; off >>= 1) {
            den += __shfl_xor(den, off);
            num += __shfl_xor(num, off);
        }
        float ampA = row[256 + tid] * 2.0f - 1.0f;   // frames 0..63
        float ampB = row[320 + tid] * 2.0f - 1.0f;   // frames 64..127
        s_amp[tid] = ampA;
        s_amp[64 + tid] = ampB;
        int h = tid & 7;                              // lanes 8..63 mirror 0..7
        float ha = row[384 + h];
        float hd = 0.5f + row[392 + h] * 0.5f;
        const float MIN_F0 = 40.0f / 11025.0f;
        const float F0_SPAN = 3000.0f / 11025.0f - 40.0f / 11025.0f;
        float f0s = num / den;
        float f0 = MIN_F0 + f0s * f0s * 11025.0f * F0_SPAN;
        float r = f0 * (float)(h + 1) * (PI_F / 11025.0f);
        float m = 1.0f;
        if (r >= PI_F) { r = 0.0f; m = 0.0f; }       // masked harmonic: sin(0)=0 in ref
        float scale = m * oamp[0];                    // fold osc_amp + mask into res
        if (tid < 8) s_rw[tid] = r;
        float cur = 0.0f;
        #pragma unroll 1
        for (int f = 0; f < 64; ++f) {
            float av = __shfl(ampA, f);
            float c = fmaxf(cur + av * ha, 0.0f);
            if (tid < 8) s_resd[h * 128 + f] = c * scale;
            cur = c * hd;
        }
        #pragma unroll 1
        for (int f = 0; f < 64; ++f) {
            float av = __shfl(ampB, f);
            float c = fmaxf(cur + av * ha, 0.0f);
            if (tid < 8) s_resd[h * 128 + 64 + f] = c * scale;
            cur = c * hd;
        }
    }
    __syncthreads();

    // --- radix-4 DIF stages ---
    r4_dif_stage<8192>(re, im, tid);
    r4_dif_stage<2048>(re, im, tid);
    r4_dif_stage<512>(re, im, tid);
    r4_dif_stage<128>(re, im, tid);
    r4_dif_stage<32>(re, im, tid);

    // --- register radix-8 DIF (half=4,2,1), scalar vars, float4 LDS I/O ---
    #pragma unroll 1
    for (int s = 0; s < 2048 / NT; ++s) {
        int m = (2048 / NT) * tid + s;
        int a = MAP(8 * m);
        float4 r0 = *(const float4*)(re + a);
        float4 r1 = *(const float4*)(re + a + 4);
        float4 q0 = *(const float4*)(im + a);
        float4 q1 = *(const float4*)(im + a + 4);
        float t0r = r0.x + r1.x, t0i = q0.x + q1.x;
        float u0r = r0.x - r1.x, u0i = q0.x - q1.x;
        float d1r = r0.y - r1.y, d1i = q0.y - q1.y;
        float t1r = r0.y + r1.y, t1i = q0.y + q1.y;
        float u1r = RT2H * (d1r + d1i), u1i = RT2H * (d1i - d1r);   // *(c-ci)
        float t2r = r0.z + r1.z, t2i = q0.z + q1.z;
        float d2r = r0.z - r1.z, d2i = q0.z - q1.z;
        float u2r = d2i, u2i = -d2r;                                  // *(-i)
        float t3r = r0.w + r1.w, t3i = q0.w + q1.w;
        float d3r = r0.w - r1.w, d3i = q0.w - q1.w;
        float u3r = RT2H * (d3i - d3r), u3i = -RT2H * (d3r + d3i);  // *(-c-ci)
        float A0r = t0r + t2r, A0i = t0i + t2i;
        float A2r = t0r - t2r, A2i = t0i - t2i;
        float A1r = t1r + t3r, A1i = t1i + t3i;
        float e3r = t1r - t3r, e3i = t1i - t3i;
        float A3r = e3i, A3i = -e3r;                                  // *(-i)
        float B0r = u0r + u2r, B0i = u0i + u2i;
        float B2r = u0r - u2r, B2i = u0i - u2i;
        float B1r = u1r + u3r, B1i = u1i + u3i;
        float f3r = u1r - u3r, f3i = u1i - u3i;
        float B3r = f3i, B3i = -f3r;
        r0.x = A0r + A1r; q0.x = A0i + A1i;
        r0.y = A0r - A1r; q0.y = A0i - A1i;
        r0.z = A2r + A3r; q0.z = A2i + A3i;
        r0.w = A2r - A3r; q0.w = A2i - A3i;
        r1.x = B0r + B1r; q1.x = B0i + B1i;
        r1.y = B0r - B1r; q1.y = B0i - B1i;
        r1.z = B2r + B3r; q1.z = B2i + B3i;
        r1.w = B2r - B3r; q1.w = B2i - B3i;
        *(float4*)(re + a) = r0; *(float4*)(re + a + 4) = r1;
        *(float4*)(im + a) = q0; *(float4*)(im + a + 4) = q1;
    }
    __syncthreads();

    // --- pointwise untangle * H * retangle, bitrev domain ---
    // NOTE: no /N_HARMONICS here! The reference broadcasts noise_out over the
    // 8-harmonic axis and sums, so the /8 cancels (R10 bug: folding 0.125 in
    // made the noise path 8x too small -> absmax 8624).
    const float invM = 1.0f / (float)FFT_M;
    #pragma unroll 1
    for (int s = 0; s < 8192 / NT; ++s) {
        int jj = (tid + s * NT) << 1;       // even position
        if (jj == 0) {
            int p0 = MAP(0);
            float z0r = re[p0], z0i = im[p0];
            float y = 0.5f * filt_at(filt, 0) * (z0r + z0i) * invM;
            re[p0] = y; im[p0] = y;
            int p1 = MAP(1);                  // k=8192 self-pair at brev(8192)=1
            float H = filt_at(filt, 8192) * invM;
            re[p1] *= H; im[p1] *= H;
        } else {
            int k = (int)(__brev((unsigned)jj) >> 18);     // k in [1,8192)
            int kq = FFT_M - k;
            int pk = MAP(jj);
            int pq = MAP((int)(__brev((unsigned)kq) >> 18));
            float zkr = re[pk], zki = im[pk];
            float zqr = re[pq], zqi = im[pq];
            float Er = 0.5f * (zkr + zqr), Ei = 0.5f * (zki - zqi);
            float Or = 0.5f * (zki + zqi), Oi = 0.5f * (zqr - zkr);
            float th = (float)k * (PI_F / (float)FFT_M);
            float s1, c1; __sincosf(th, &s1, &c1);
            float ts = -s1;
            float tOr = c1 * Or - ts * Oi;
            float tOi = c1 * Oi + ts * Or;
            float Hk = filt_at(filt, k);
            float Hq = filt_at(filt, kq);
            float Ykr = Hk * (Er + tOr), Yki = Hk * (Ei + tOi);
            float Cr  = Hq * (Er - tOr), Ci  = Hq * (Ei - tOi);
            float Ar = 0.5f * (Ykr + Cr), Ai = 0.5f * (Yki + Ci);
            float Br = 0.5f * (Ykr - Cr), Bi = 0.5f * (Yki - Ci);
            re[pk] = (Ar + ts * Br - c1 * Bi) * invM;
            im[pk] = (Ai + c1 * Br + ts * Bi) * invM;
            re[pq] = (Ar + c1 * Bi - ts * Br) * invM;
            im[pq] = (-Ai + c1 * Br + ts * Bi) * invM;
        }
    }
    __syncthreads();

    // --- register radix-8 DIT (half=1,2,4), scalar vars ---
    #pragma unroll 1
    for (int s = 0; s < 2048 / NT; ++s) {
        int m = (2048 / NT) * tid + s;
        int a = MAP(8 * m);
        float4 r0 = *(const float4*)(re + a);
        float4 r1 = *(const float4*)(re + a + 4);
        float4 q0 = *(const float4*)(im + a);
        float4 q1 = *(const float4*)(im + a + 4);
        float A0r = r0.x + r0.y, A0i = q0.x + q0.y;
        float A1r = r0.x - r0.y, A1i = q0.x - q0.y;
        float A2r = r0.z + r0.w, A2i = q0.z + q0.w;
        float A3r = r0.z - r0.w, A3i = q0.z - q0.w;
        float B0r = r1.x + r1.y, B0i = q1.x + q1.y;
        float B1r = r1.x - r1.y, B1i = q1.x - q1.y;
        float B2r = r1.z + r1.w, B2i = q1.z + q1.w;
        float B3r = r1.z - r1.w, B3i = q1.z - q1.w;
        float t0r = A0r + A2r, t0i = A0i + A2i;
        float t2r = A0r - A2r, t2i = A0i - A2i;
        float w3r = -A3i, w3i = A3r;
        float t1r = A1r + w3r, t1i = A1i + w3i;
        float t3r = A1r - w3r, t3i = A1i - w3i;
        float u0r = B0r + B2r, u0i = B0i + B2i;
        float u2r = B0r - B2r, u2i = B0i - B2i;
        float x3r = -B3i, x3i = B3r;
        float u1r = B1r + x3r, u1i = B1i + x3i;
        float u3r = B1r - x3r, u3i = B1i - x3i;
        float w1r = RT2H * (u1r - u1i), w1i = RT2H * (u1r + u1i);
        float w2r = -u2i,               w2i = u2r;
        float w5r = RT2H * (-u3r - u3i), w5i = RT2H * (u3r - u3i);
        r0.x = t0r + u0r; q0.x = t0i + u0i;
        r1.x = t0r - u0r; q1.x = t0i - u0i;
        r0.y = t1r + w1r; q0.y = t1i + w1i;
        r1.y = t1r - w1r; q1.y = t1i - w1i;
        r0.z = t2r + w2r; q0.z = t2i + w2i;
        r1.z = t2r - w2r; q1.z = t2i - w2i;
        r0.w = t3r + w5r; q0.w = t3i + w5i;
        r1.w = t3r - w5r; q1.w = t3i - w5i;
        *(float4*)(re + a) = r0; *(float4*)(re + a + 4) = r1;
        *(float4*)(im + a) = q0; *(float4*)(im + a + 4) = q1;
    }
    __syncthreads();

    // --- radix-4 DIT stages ---
    r4_dit_stage<32>(re, im, tid);
    r4_dit_stage<128>(re, im, tid);
    r4_dit_stage<512>(re, im, tid);
    r4_dit_stage<2048>(re, im, tid);
    r4_dit_stage<8192>(re, im, tid);

    // --- epilogue: fused final r2 DIT + amp-gate + harmonic bank + atomicAdd ---
    // Thread t owns j in [8t, 8t+8): run0 -> time samples [16t,16t+16),
    // run1 -> [16384+16t, 16384+16t+16). Per-sample sine via rotation
    // recurrence (no sincos), Chebyshev over the 8 harmonics.
    {
        float* outg = out + (size_t)(b >> 3) * N_SAMPLES;
        const float r1v = s_rw[0];
        float rs, rc; __sincosf(r1v, &rs, &rc);       // rotation step by r1
        #pragma unroll 1
        for (int run = 0; run < 2; ++run) {
            const int tbase = 16 * tid + run * 16384;
            float sn, cn; __sincosf((float)(tbase + 1) * r1v, &sn, &cn);
            int cur = -1;
            float Ah[8], Bh[8];
            float aA = 0.0f, aB = 0.0f;
            #pragma unroll 1
            for (int s = 0; s < 8; ++s) {
                const int j = 8 * tid + s;
                const int a0 = MAP(j), a1 = MAP(j + 8192);
                float ur = re[a0], ui = im[a0];
                float xr = re[a1], xi = im[a1];
                float s1, c1; __sincosf((PI_F / 8192.0f) * (float)j, &s1, &c1);
                float wr = xr * c1 - xi * s1, wi = xr * s1 + xi * c1;
                float vre = run ? (ur - wr) : (ur + wr);
                float vim = run ? (ui - wi) : (ui + wi);
                float vv0 = vre, vv1 = vim;
                #pragma unroll
                for (int ci = 0; ci < 2; ++ci) {
                    const int n = tbase + 2 * s + ci;
                    float coords = ((float)n + 0.5f) * (1.0f / 256.0f) - 0.5f;
                    coords = fminf(fmaxf(coords, 0.0f), 127.0f);
                    int i0 = (int)floorf(coords);
                    float w = coords - (float)i0;
                    if (i0 != cur) {
                        cur = i0;
                        int i1 = min(i0 + 1, 127);
                        aA = s_amp[i0]; aB = s_amp[i1] - aA;
                        #pragma unroll
                        for (int h = 0; h < 8; ++h) {
                            float a = s_resd[h * 128 + i0];
                            Ah[h] = a;
                            Bh[h] = s_resd[h * 128 + i1] - a;
                        }
                    }
                    float av = aA + w * aB;
                    float gate = (av >= 0.0f) ? av : 0.2f * av;
                    float acc = (ci ? vv1 : vv0) * gate;
                    float c2x = 2.0f * cn;
                    float shm1 = 0.0f, sh = sn;
                    #pragma unroll
                    for (int h = 0; h < 8; ++h) {
                        acc += (Ah[h] + w * Bh[h]) * sh;
                        float nx = c2x * sh - shm1;
                        shm1 = sh; sh = nx;
                    }
                    atomicAdd(&outg[n], acc);
                    float ns = sn * rc + cn * rs;     // advance phase by r1
                    float nc = cn * rc - sn * rs;
                    sn = ns; cn = nc;
                }
            }
        }
    }
}

extern "C" void kernel_launch(void* const* d_in, const int* in_sizes, int n_in,
                              void* d_out, int out_size, void* d_ws, size_t ws_size,
                              hipStream_t stream) {
    const float* packed = (const float*)d_in[0];
    const float* freqs  = (const float*)d_in[1];
    const float* gamp   = (const float*)d_in[2];
    const float* oamp   = (const float*)d_in[3];
    const float* noise  = (const float*)d_in[4];
    float* out = (float*)d_out;

    hipMemsetAsync(out, 0, (size_t)out_size * sizeof(float), stream);
    fft_filter_kernel<<<B_EVENTS, NT, LDS_TOTAL * sizeof(float), stream>>>(
        noise, packed, gamp, oamp, freqs, out);
}

// Round 12
// 126.730 us; speedup vs baseline: 2.4145x; 2.4145x over previous
//
#include <hip/hip_runtime.h>
#include <math.h>

#define PCK_STRIDE 416
#define N_SAMPLES  32768
#define FFT_M      16384        // complex FFT size (real packing)
#define B_EVENTS   128
#define N_GROUPS   16
#define NT         1024
#define PI_F 3.14159265358979323846f
#define RT2H 0.70710678118654752f   // sqrt(2)/2

// LDS padded mapping: +4 floats per 32-block (keeps 8-blocks contiguous and
// 16B-aligned; all r4/r8 accesses <=2-way bank aliasing).
#define MAP(i) ((i) + (((i) >> 5) << 2))
#define LDS_N  18432            // 16384 + 2048 pad
// LDS floats: re/im (2*18432) + filt 16 + s_res 1024 + s_amp 128 + s_rw 8
#define LDS_TOTAL (2 * LDS_N + 16 + 1024 + 128 + 8)   // 38040 floats = 152160 B < 160 KB

__device__ inline float filt_at(const float* __restrict__ f, int k) {
    if (k >= FFT_M) return 0.0f;
    float c = ((float)k + 0.5f) * (1.0f / 1024.0f) - 0.5f;
    c = fminf(fmaxf(c, 0.0f), 15.0f);
    int i0 = (int)floorf(c);
    int i1 = min(i0 + 1, 15);
    float w = c - (float)i0;
    return f[i0] * (1.0f - w) + f[i1] * w;
}

// ---------------- radix-4 LDS stages ----------------
// unroll 1: fits the 64-VGPR budget the allocator pins for 1024-thread
// blocks (R6/R8/R9 evidence). 16 waves/CU supply latency hiding.
template<int L>
__device__ inline void r4_dif_stage(float* re, float* im, int tid) {
    constexpr int q = L >> 2;
    constexpr float ang = -6.28318530717958647692f / (float)L;
    #pragma unroll 1
    for (int s = 0; s < (FFT_M / 4) / NT; ++s) {
        int m = tid + s * NT;
        int t = m & (q - 1);
        int i0 = ((m & ~(q - 1)) << 2) | t;
        int ia = MAP(i0), ib = MAP(i0 + q), ic = MAP(i0 + 2 * q), id = MAP(i0 + 3 * q);
        float ar = re[ia], ai = im[ia];
        float br = re[ib], bi = im[ib];
        float cr = re[ic], ci = im[ic];
        float dr = re[id], di = im[id];
        float s1, c1; __sincosf(ang * (float)t, &s1, &c1);
        float c2 = c1 * c1 - s1 * s1, s2 = 2.0f * c1 * s1;
        float c3 = c2 * c1 - s2 * s1, s3 = c2 * s1 + s2 * c1;
        float s0r = ar + cr, s0i = ai + ci;
        float t1r = br + dr, t1i = bi + di;
        float d0r = ar - cr, d0i = ai - ci;
        float d1r = br - dr, d1i = bi - di;
        re[ia] = s0r + t1r; im[ia] = s0i + t1i;
        float er = s0r - t1r, ei = s0i - t1i;
        re[ib] = er * c2 - ei * s2; im[ib] = er * s2 + ei * c2;
        float fr = d0r + d1i, fi = d0i - d1r;   // (a-c) - i(b-d)
        re[ic] = fr * c1 - fi * s1; im[ic] = fr * s1 + fi * c1;
        float gr = d0r - d1i, gi = d0i + d1r;   // (a-c) + i(b-d)
        re[id] = gr * c3 - gi * s3; im[id] = gr * s3 + gi * c3;
    }
    __syncthreads();
}

template<int L>
__device__ inline void r4_dit_stage(float* re, float* im, int tid) {
    constexpr int q = L >> 2;
    constexpr float ang = 6.28318530717958647692f / (float)L;
    #pragma unroll 1
    for (int s = 0; s < (FFT_M / 4) / NT; ++s) {
        int m = tid + s * NT;
        int t = m & (q - 1);
        int i0 = ((m & ~(q - 1)) << 2) | t;
        int ia = MAP(i0), ib = MAP(i0 + q), ic = MAP(i0 + 2 * q), id = MAP(i0 + 3 * q);
        float ar = re[ia], ai = im[ia];
        float br = re[ib], bi = im[ib];
        float cr = re[ic], ci = im[ic];
        float dr = re[id], di = im[id];
        float s1, c1; __sincosf(ang * (float)t, &s1, &c1);
        float c2 = c1 * c1 - s1 * s1, s2 = 2.0f * c1 * s1;
        float tbr = br * c2 - bi * s2, tbi = br * s2 + bi * c2;
        float tdr = dr * c2 - di * s2, tdi = dr * s2 + di * c2;
        float B0r = ar + tbr, B0i = ai + tbi;
        float B1r = ar - tbr, B1i = ai - tbi;
        float B2r = cr + tdr, B2i = ci + tdi;
        float B3r = cr - tdr, B3i = ci - tdi;
        float t0r = B2r * c1 - B2i * s1, t0i = B2r * s1 + B2i * c1;
        float t1r = -B3r * s1 - B3i * c1, t1i = B3r * c1 - B3i * s1;  // B3*(i*w1)
        re[ia] = B0r + t0r; im[ia] = B0i + t0i;
        re[ib] = B1r + t1r; im[ib] = B1i + t1i;
        re[ic] = B0r - t0r; im[ic] = B0i - t0i;
        re[id] = B1r - t1r; im[id] = B1i - t1i;
    }
    __syncthreads();
}

// ---------------- K1: FFT filter + fused prep + fused gate/harmonic epilogue ----
// Writes each event's finished per-sample contribution to ws (plain coalesced
// stores -- R11's cross-XCD atomicAdd caused 134 MB of RMW line ping-pong).
__global__ __launch_bounds__(NT)
void fft_filter_kernel(
    const float* __restrict__ noise, const float* __restrict__ packed,
    const float* __restrict__ gamp, const float* __restrict__ oamp,
    const float* __restrict__ freqs, float* __restrict__ evout)
{
    extern __shared__ float smem[];
    float* re = smem;
    float* im = smem + LDS_N;
    float* filt   = smem + 2 * LDS_N;       // 16
    float* s_resd = filt + 16;              // [8][128] pre-scaled by osc_amp*mask
    float* s_amp  = s_resd + 1024;          // 128 gated-amp frames (2x-1)
    float* s_rw   = s_amp + 128;            // 8 radians
    const int b = blockIdx.x;
    const int tid = threadIdx.x;
    const float g = gamp[0];

    // --- load + fused r2 DIF (half=8192) ---
    const float2* nz = (const float2*)(noise + (size_t)b * N_SAMPLES);
    #pragma unroll 1
    for (int s = 0; s < 8192 / NT; ++s) {
        int j = tid + s * NT;
        float2 v0 = nz[j];
        float2 v1 = nz[j + 8192];
        float ur = v0.x * g, ui = v0.y * g;
        float wr = v1.x * g, wi = v1.y * g;
        float s1, c1; __sincosf((-PI_F / 8192.0f) * (float)j, &s1, &c1);
        int a0 = MAP(j), a1 = MAP(j + 8192);
        re[a0] = ur + wr; im[a0] = ui + wi;
        float dr = ur - wr, di = ui - wi;
        re[a1] = dr * c1 - di * s1;
        im[a1] = dr * s1 + di * c1;
    }
    if (tid >= 64 && tid < 80) filt[tid - 64] = packed[b * PCK_STRIDE + 400 + (tid - 64)];

    // --- fused prep on wave 0 (shuffle-only): softmax-f0, radians, decay scan -> LDS ---
    if (tid < 64) {
        const float* row = packed + b * PCK_STRIDE;
        float n0 = row[tid], n1 = row[tid + 64];
        float fq0 = freqs[tid], fq1 = freqs[tid + 64];
        float mx = fmaxf(n0, n1);
        #pragma unroll
        for (int off = 32; off >= 1; off >>= 1) mx = fmaxf(mx, __shfl_xor(mx, off));
        float e0 = __expf(n0 - mx), e1 = __expf(n1 - mx);
        float den = e0 + e1, num = e0 * fq0 + e1 * fq1;
        #pragma unroll
        for (int off = 32; off >= 1; off >>= 1) {
            den += __shfl_xor(den, off);
            num += __shfl_xor(num, off);
        }
        float ampA = row[256 + tid] * 2.0f - 1.0f;   // frames 0..63
        float ampB = row[320 + tid] * 2.0f - 1.0f;   // frames 64..127
        s_amp[tid] = ampA;
        s_amp[64 + tid] = ampB;
        int h = tid & 7;                              // lanes 8..63 mirror 0..7
        float ha = row[384 + h];
        float hd = 0.5f + row[392 + h] * 0.5f;
        const float MIN_F0 = 40.0f / 11025.0f;
        const float F0_SPAN = 3000.0f / 11025.0f - 40.0f / 11025.0f;
        float f0s = num / den;
        float f0 = MIN_F0 + f0s * f0s * 11025.0f * F0_SPAN;
        float r = f0 * (float)(h + 1) * (PI_F / 11025.0f);
        float m = 1.0f;
        if (r >= PI_F) { r = 0.0f; m = 0.0f; }       // masked harmonic: sin(0)=0 in ref
        float scale = m * oamp[0];                    // fold osc_amp + mask into res
        if (tid < 8) s_rw[tid] = r;
        float cur = 0.0f;
        #pragma unroll 1
        for (int f = 0; f < 64; ++f) {
            float av = __shfl(ampA, f);
            float c = fmaxf(cur + av * ha, 0.0f);
            if (tid < 8) s_resd[h * 128 + f] = c * scale;
            cur = c * hd;
        }
        #pragma unroll 1
        for (int f = 0; f < 64; ++f) {
            float av = __shfl(ampB, f);
            float c = fmaxf(cur + av * ha, 0.0f);
            if (tid < 8) s_resd[h * 128 + 64 + f] = c * scale;
            cur = c * hd;
        }
    }
    __syncthreads();

    // --- radix-4 DIF stages ---
    r4_dif_stage<8192>(re, im, tid);
    r4_dif_stage<2048>(re, im, tid);
    r4_dif_stage<512>(re, im, tid);
    r4_dif_stage<128>(re, im, tid);
    r4_dif_stage<32>(re, im, tid);

    // --- register radix-8 DIF (half=4,2,1), scalar vars, float4 LDS I/O ---
    #pragma unroll 1
    for (int s = 0; s < 2048 / NT; ++s) {
        int m = (2048 / NT) * tid + s;
        int a = MAP(8 * m);
        float4 r0 = *(const float4*)(re + a);
        float4 r1 = *(const float4*)(re + a + 4);
        float4 q0 = *(const float4*)(im + a);
        float4 q1 = *(const float4*)(im + a + 4);
        float t0r = r0.x + r1.x, t0i = q0.x + q1.x;
        float u0r = r0.x - r1.x, u0i = q0.x - q1.x;
        float d1r = r0.y - r1.y, d1i = q0.y - q1.y;
        float t1r = r0.y + r1.y, t1i = q0.y + q1.y;
        float u1r = RT2H * (d1r + d1i), u1i = RT2H * (d1i - d1r);   // *(c-ci)
        float t2r = r0.z + r1.z, t2i = q0.z + q1.z;
        float d2r = r0.z - r1.z, d2i = q0.z - q1.z;
        float u2r = d2i, u2i = -d2r;                                  // *(-i)
        float t3r = r0.w + r1.w, t3i = q0.w + q1.w;
        float d3r = r0.w - r1.w, d3i = q0.w - q1.w;
        float u3r = RT2H * (d3i - d3r), u3i = -RT2H * (d3r + d3i);  // *(-c-ci)
        float A0r = t0r + t2r, A0i = t0i + t2i;
        float A2r = t0r - t2r, A2i = t0i - t2i;
        float A1r = t1r + t3r, A1i = t1i + t3i;
        float e3r = t1r - t3r, e3i = t1i - t3i;
        float A3r = e3i, A3i = -e3r;                                  // *(-i)
        float B0r = u0r + u2r, B0i = u0i + u2i;
        float B2r = u0r - u2r, B2i = u0i - u2i;
        float B1r = u1r + u3r, B1i = u1i + u3i;
        float f3r = u1r - u3r, f3i = u1i - u3i;
        float B3r = f3i, B3i = -f3r;
        r0.x = A0r + A1r; q0.x = A0i + A1i;
        r0.y = A0r - A1r; q0.y = A0i - A1i;
        r0.z = A2r + A3r; q0.z = A2i + A3i;
        r0.w = A2r - A3r; q0.w = A2i - A3i;
        r1.x = B0r + B1r; q1.x = B0i + B1i;
        r1.y = B0r - B1r; q1.y = B0i - B1i;
        r1.z = B2r + B3r; q1.z = B2i + B3i;
        r1.w = B2r - B3r; q1.w = B2i - B3i;
        *(float4*)(re + a) = r0; *(float4*)(re + a + 4) = r1;
        *(float4*)(im + a) = q0; *(float4*)(im + a + 4) = q1;
    }
    __syncthreads();

    // --- pointwise untangle * H * retangle, bitrev domain ---
    // No /N_HARMONICS: the reference broadcasts noise over the 8-harmonic
    // axis then sums, so the /8 cancels (R10 lesson).
    const float invM = 1.0f / (float)FFT_M;
    #pragma unroll 1
    for (int s = 0; s < 8192 / NT; ++s) {
        int jj = (tid + s * NT) << 1;       // even position
        if (jj == 0) {
            int p0 = MAP(0);
            float z0r = re[p0], z0i = im[p0];
            float y = 0.5f * filt_at(filt, 0) * (z0r + z0i) * invM;
            re[p0] = y; im[p0] = y;
            int p1 = MAP(1);                  // k=8192 self-pair at brev(8192)=1
            float H = filt_at(filt, 8192) * invM;
            re[p1] *= H; im[p1] *= H;
        } else {
            int k = (int)(__brev((unsigned)jj) >> 18);     // k in [1,8192)
            int kq = FFT_M - k;
            int pk = MAP(jj);
            int pq = MAP((int)(__brev((unsigned)kq) >> 18));
            float zkr = re[pk], zki = im[pk];
            float zqr = re[pq], zqi = im[pq];
            float Er = 0.5f * (zkr + zqr), Ei = 0.5f * (zki - zqi);
            float Or = 0.5f * (zki + zqi), Oi = 0.5f * (zqr - zkr);
            float th = (float)k * (PI_F / (float)FFT_M);
            float s1, c1; __sincosf(th, &s1, &c1);
            float ts = -s1;
            float tOr = c1 * Or - ts * Oi;
            float tOi = c1 * Oi + ts * Or;
            float Hk = filt_at(filt, k);
            float Hq = filt_at(filt, kq);
            float Ykr = Hk * (Er + tOr), Yki = Hk * (Ei + tOi);
            float Cr  = Hq * (Er - tOr), Ci  = Hq * (Ei - tOi);
            float Ar = 0.5f * (Ykr + Cr), Ai = 0.5f * (Yki + Ci);
            float Br = 0.5f * (Ykr - Cr), Bi = 0.5f * (Yki - Ci);
            re[pk] = (Ar + ts * Br - c1 * Bi) * invM;
            im[pk] = (Ai + c1 * Br + ts * Bi) * invM;
            re[pq] = (Ar + c1 * Bi - ts * Br) * invM;
            im[pq] = (-Ai + c1 * Br + ts * Bi) * invM;
        }
    }
    __syncthreads();

    // --- register radix-8 DIT (half=1,2,4), scalar vars ---
    #pragma unroll 1
    for (int s = 0; s < 2048 / NT; ++s) {
        int m = (2048 / NT) * tid + s;
        int a = MAP(8 * m);
        float4 r0 = *(const float4*)(re + a);
        float4 r1 = *(const float4*)(re + a + 4);
        float4 q0 = *(const float4*)(im + a);
        float4 q1 = *(const float4*)(im + a + 4);
        float A0r = r0.x + r0.y, A0i = q0.x + q0.y;
        float A1r = r0.x - r0.y, A1i = q0.x - q0.y;
        float A2r = r0.z + r0.w, A2i = q0.z + q0.w;
        float A3r = r0.z - r0.w, A3i = q0.z - q0.w;
        float B0r = r1.x + r1.y, B0i = q1.x + q1.y;
        float B1r = r1.x - r1.y, B1i = q1.x - q1.y;
        float B2r = r1.z + r1.w, B2i = q1.z + q1.w;
        float B3r = r1.z - r1.w, B3i = q1.z - q1.w;
        float t0r = A0r + A2r, t0i = A0i + A2i;
        float t2r = A0r - A2r, t2i = A0i - A2i;
        float w3r = -A3i, w3i = A3r;
        float t1r = A1r + w3r, t1i = A1i + w3i;
        float t3r = A1r - w3r, t3i = A1i - w3i;
        float u0r = B0r + B2r, u0i = B0i + B2i;
        float u2r = B0r - B2r, u2i = B0i - B2i;
        float x3r = -B3i, x3i = B3r;
        float u1r = B1r + x3r, u1i = B1i + x3i;
        float u3r = B1r - x3r, u3i = B1i - x3i;
        float w1r = RT2H * (u1r - u1i), w1i = RT2H * (u1r + u1i);
        float w2r = -u2i,               w2i = u2r;
        float w5r = RT2H * (-u3r - u3i), w5i = RT2H * (u3r - u3i);
        r0.x = t0r + u0r; q0.x = t0i + u0i;
        r1.x = t0r - u0r; q1.x = t0i - u0i;
        r0.y = t1r + w1r; q0.y = t1i + w1i;
        r1.y = t1r - w1r; q1.y = t1i - w1i;
        r0.z = t2r + w2r; q0.z = t2i + w2i;
        r1.z = t2r - w2r; q1.z = t2i - w2i;
        r0.w = t3r + w5r; q0.w = t3i + w5i;
        r1.w = t3r - w5r; q1.w = t3i - w5i;
        *(float4*)(re + a) = r0; *(float4*)(re + a + 4) = r1;
        *(float4*)(im + a) = q0; *(float4*)(im + a + 4) = q1;
    }
    __syncthreads();

    // --- radix-4 DIT stages ---
    r4_dit_stage<32>(re, im, tid);
    r4_dit_stage<128>(re, im, tid);
    r4_dit_stage<512>(re, im, tid);
    r4_dit_stage<2048>(re, im, tid);
    r4_dit_stage<8192>(re, im, tid);

    // --- epilogue: fused final r2 DIT + amp-gate + harmonic bank -> evout[b] ---
    // Thread t owns j in [8t,8t+8): run0 -> samples [16t,16t+16), run1 ->
    // [16384+16t,...). Per-sample sine via rotation recurrence + Chebyshev.
    {
        float* eb = evout + (size_t)b * N_SAMPLES;
        const float r1v = s_rw[0];
        float rs, rc; __sincosf(r1v, &rs, &rc);       // rotation step by r1
        #pragma unroll 1
        for (int run = 0; run < 2; ++run) {
            const int tbase = 16 * tid + run * 16384;
            float sn, cn; __sincosf((float)(tbase + 1) * r1v, &sn, &cn);
            int cur = -1;
            float Ah[8], Bh[8];
            float aA = 0.0f, aB = 0.0f;
            #pragma unroll 1
            for (int s = 0; s < 8; ++s) {
                const int j = 8 * tid + s;
                const int a0 = MAP(j), a1 = MAP(j + 8192);
                float ur = re[a0], ui = im[a0];
                float xr = re[a1], xi = im[a1];
                float s1, c1; __sincosf((PI_F / 8192.0f) * (float)j, &s1, &c1);
                float wr = xr * c1 - xi * s1, wi = xr * s1 + xi * c1;
                float vv0 = run ? (ur - wr) : (ur + wr);
                float vv1 = run ? (ui - wi) : (ui + wi);
                float o0 = 0.0f, o1 = 0.0f;
                #pragma unroll
                for (int ci = 0; ci < 2; ++ci) {
                    const int n = tbase + 2 * s + ci;
                    float coords = ((float)n + 0.5f) * (1.0f / 256.0f) - 0.5f;
                    coords = fminf(fmaxf(coords, 0.0f), 127.0f);
                    int i0 = (int)floorf(coords);
                    float w = coords - (float)i0;
                    if (i0 != cur) {
                        cur = i0;
                        int i1 = min(i0 + 1, 127);
                        aA = s_amp[i0]; aB = s_amp[i1] - aA;
                        #pragma unroll
                        for (int h = 0; h < 8; ++h) {
                            float a = s_resd[h * 128 + i0];
                            Ah[h] = a;
                            Bh[h] = s_resd[h * 128 + i1] - a;
                        }
                    }
                    float av = aA + w * aB;
                    float gate = (av >= 0.0f) ? av : 0.2f * av;
                    float acc = (ci ? vv1 : vv0) * gate;
                    float c2x = 2.0f * cn;
                    float shm1 = 0.0f, sh = sn;
                    #pragma unroll
                    for (int h = 0; h < 8; ++h) {
                        acc += (Ah[h] + w * Bh[h]) * sh;
                        float nx = c2x * sh - shm1;
                        shm1 = sh; sh = nx;
                    }
                    if (ci) o1 = acc; else o0 = acc;
                    float ns = sn * rc + cn * rs;     // advance phase by r1
                    float nc = cn * rc - sn * rs;
                    sn = ns; cn = nc;
                }
                *(float2*)(eb + tbase + 2 * s) = make_float2(o0, o1);
            }
        }
    }
}

// ---------------- K2: reduce 8 events -> group output (pure streaming) ----------------
__global__ __launch_bounds__(256) void reduce_kernel(
    const float* __restrict__ evout, float* __restrict__ out)
{
    const int idx = blockIdx.x * 256 + threadIdx.x;   // float4 index in [0, 16*8192)
    const int g = idx >> 13;                           // 8192 float4 per group
    const int q = idx & 8191;
    const float4* base = (const float4*)(evout + (size_t)g * 8 * N_SAMPLES) + q;
    float4 a = base[0];
    #pragma unroll
    for (int e = 1; e < 8; ++e) {
        float4 v = base[(size_t)e * (N_SAMPLES / 4)];
        a.x += v.x; a.y += v.y; a.z += v.z; a.w += v.w;
    }
    ((float4*)out)[idx] = a;
}

extern "C" void kernel_launch(void* const* d_in, const int* in_sizes, int n_in,
                              void* d_out, int out_size, void* d_ws, size_t ws_size,
                              hipStream_t stream) {
    const float* packed = (const float*)d_in[0];
    const float* freqs  = (const float*)d_in[1];
    const float* gamp   = (const float*)d_in[2];
    const float* oamp   = (const float*)d_in[3];
    const float* noise  = (const float*)d_in[4];
    float* out = (float*)d_out;
    float* evout = (float*)d_ws;                       // 128*32768 floats (16 MB)

    fft_filter_kernel<<<B_EVENTS, NT, LDS_TOTAL * sizeof(float), stream>>>(
        noise, packed, gamp, oamp, freqs, evout);
    reduce_kernel<<<(N_GROUPS * N_SAMPLES / 4) / 256, 256, 0, stream>>>(evout, out);
}

// Round 13
// 118.540 us; speedup vs baseline: 2.5814x; 1.0691x over previous
//
#include <hip/hip_runtime.h>
#include <math.h>

#define PCK_STRIDE 416
#define N_SAMPLES  32768
#define FFT_M      16384        // complex FFT size (real packing)
#define B_EVENTS   128
#define N_GROUPS   16
#define NT         1024
#define PI_F 3.14159265358979323846f
#define RT2H 0.70710678118654752f   // sqrt(2)/2

// Interleaved complex LDS (float2), padded +1 float2 per 8: halves the LDS
// instruction count vs split re/im b32 arrays (R13 change). Injective,
// max MP(16383)=18430 < 18432. 8-blocks stay contiguous for the r8 phase.
#define MP(i) ((i) + ((i) >> 3))
#define LDS_Z  18432            // float2 slots = 147456 B; +filt 64 B
#define LDS_BYTES (LDS_Z * 8 + 16 * 4)

__device__ inline float filt_at(const float* __restrict__ f, int k) {
    if (k >= FFT_M) return 0.0f;
    float c = ((float)k + 0.5f) * (1.0f / 1024.0f) - 0.5f;
    c = fminf(fmaxf(c, 0.0f), 15.0f);
    int i0 = (int)floorf(c);
    int i1 = min(i0 + 1, 15);
    float w = c - (float)i0;
    return f[i0] * (1.0f - w) + f[i1] * w;
}

// ---------------- radix-4 LDS stages (unroll 1: fits 64-VGPR budget at NT=1024) ----
template<int L>
__device__ inline void r4_dif_stage(float2* zz, int tid) {
    constexpr int q = L >> 2;
    constexpr float ang = -6.28318530717958647692f / (float)L;
    #pragma unroll 1
    for (int s = 0; s < (FFT_M / 4) / NT; ++s) {
        int m = tid + s * NT;
        int t = m & (q - 1);
        int i0 = ((m & ~(q - 1)) << 2) | t;
        int ia = MP(i0), ib = MP(i0 + q), ic = MP(i0 + 2 * q), id = MP(i0 + 3 * q);
        float2 va = zz[ia], vb = zz[ib], vc = zz[ic], vd = zz[id];
        float s1, c1; __sincosf(ang * (float)t, &s1, &c1);
        float c2 = c1 * c1 - s1 * s1, s2 = 2.0f * c1 * s1;
        float c3 = c2 * c1 - s2 * s1, s3 = c2 * s1 + s2 * c1;
        float s0r = va.x + vc.x, s0i = va.y + vc.y;
        float t1r = vb.x + vd.x, t1i = vb.y + vd.y;
        float d0r = va.x - vc.x, d0i = va.y - vc.y;
        float d1r = vb.x - vd.x, d1i = vb.y - vd.y;
        zz[ia] = make_float2(s0r + t1r, s0i + t1i);
        float er = s0r - t1r, ei = s0i - t1i;
        zz[ib] = make_float2(er * c2 - ei * s2, er * s2 + ei * c2);
        float fr = d0r + d1i, fi = d0i - d1r;   // (a-c) - i(b-d)
        zz[ic] = make_float2(fr * c1 - fi * s1, fr * s1 + fi * c1);
        float gr = d0r - d1i, gi = d0i + d1r;   // (a-c) + i(b-d)
        zz[id] = make_float2(gr * c3 - gi * s3, gr * s3 + gi * c3);
    }
    __syncthreads();
}

template<int L>
__device__ inline void r4_dit_stage(float2* zz, int tid) {
    constexpr int q = L >> 2;
    constexpr float ang = 6.28318530717958647692f / (float)L;
    #pragma unroll 1
    for (int s = 0; s < (FFT_M / 4) / NT; ++s) {
        int m = tid + s * NT;
        int t = m & (q - 1);
        int i0 = ((m & ~(q - 1)) << 2) | t;
        int ia = MP(i0), ib = MP(i0 + q), ic = MP(i0 + 2 * q), id = MP(i0 + 3 * q);
        float2 va = zz[ia], vb = zz[ib], vc = zz[ic], vd = zz[id];
        float s1, c1; __sincosf(ang * (float)t, &s1, &c1);
        float c2 = c1 * c1 - s1 * s1, s2 = 2.0f * c1 * s1;
        float tbr = vb.x * c2 - vb.y * s2, tbi = vb.x * s2 + vb.y * c2;
        float tdr = vd.x * c2 - vd.y * s2, tdi = vd.x * s2 + vd.y * c2;
        float B0r = va.x + tbr, B0i = va.y + tbi;
        float B1r = va.x - tbr, B1i = va.y - tbi;
        float B2r = vc.x + tdr, B2i = vc.y + tdi;
        float B3r = vc.x - tdr, B3i = vc.y - tdi;
        float t0r = B2r * c1 - B2i * s1, t0i = B2r * s1 + B2i * c1;
        float t1r = -B3r * s1 - B3i * c1, t1i = B3r * c1 - B3i * s1;  // B3*(i*w1)
        zz[ia] = make_float2(B0r + t0r, B0i + t0i);
        zz[ib] = make_float2(B1r + t1r, B1i + t1i);
        zz[ic] = make_float2(B0r - t0r, B0i - t0i);
        zz[id] = make_float2(B1r - t1r, B1i - t1i);
    }
    __syncthreads();
}

// ---------------- K1: 16384-pt FFT filter + fused prep (wave 0) ----------------
__global__ __launch_bounds__(NT)
void fft_filter_kernel(
    const float* __restrict__ noise, const float* __restrict__ packed,
    const float* __restrict__ gamp, float* __restrict__ noise_out,
    const float* __restrict__ freqs, float* __restrict__ rW, float* __restrict__ res)
{
    extern __shared__ float smem[];
    float2* zz = (float2*)smem;
    float* filt = smem + 2 * LDS_Z;
    const int b = blockIdx.x;
    const int tid = threadIdx.x;
    const float g = gamp[0];

    // --- load + fused r2 DIF (half=8192) ---
    const float2* nz = (const float2*)(noise + (size_t)b * N_SAMPLES);
    #pragma unroll 1
    for (int s = 0; s < 8192 / NT; ++s) {
        int j = tid + s * NT;
        float2 v0 = nz[j];
        float2 v1 = nz[j + 8192];
        float ur = v0.x * g, ui = v0.y * g;
        float wr = v1.x * g, wi = v1.y * g;
        float s1, c1; __sincosf((-PI_F / 8192.0f) * (float)j, &s1, &c1);
        float dr = ur - wr, di = ui - wi;
        zz[MP(j)] = make_float2(ur + wr, ui + wi);
        zz[MP(j + 8192)] = make_float2(dr * c1 - di * s1, dr * s1 + di * c1);
    }
    if (tid >= 64 && tid < 80) filt[tid - 64] = packed[b * PCK_STRIDE + 400 + (tid - 64)];

    // --- fused prep on wave 0 (shuffle-only, no extra barriers) ---
    if (tid < 64) {
        const float* row = packed + b * PCK_STRIDE;
        float n0 = row[tid], n1 = row[tid + 64];
        float fq0 = freqs[tid], fq1 = freqs[tid + 64];
        float mx = fmaxf(n0, n1);
        #pragma unroll
        for (int off = 32; off >= 1; off >>= 1) mx = fmaxf(mx, __shfl_xor(mx, off));
        float e0 = __expf(n0 - mx), e1 = __expf(n1 - mx);
        float den = e0 + e1, num = e0 * fq0 + e1 * fq1;
        #pragma unroll
        for (int off = 32; off >= 1; off >>= 1) {
            den += __shfl_xor(den, off);
            num += __shfl_xor(num, off);
        }
        float ampA = row[256 + tid] * 2.0f - 1.0f;   // frames 0..63
        float ampB = row[320 + tid] * 2.0f - 1.0f;   // frames 64..127
        int h = tid & 7;                              // lanes 8..63 mirror 0..7
        float ha = row[384 + h];
        float hd = 0.5f + row[392 + h] * 0.5f;
        const float MIN_F0 = 40.0f / 11025.0f;
        const float F0_SPAN = 3000.0f / 11025.0f - 40.0f / 11025.0f;
        float f0s = num / den;
        float f0 = MIN_F0 + f0s * f0s * 11025.0f * F0_SPAN;
        float r = f0 * (float)(h + 1) * (PI_F / 11025.0f);
        if (r >= PI_F) r = 0.0f;
        if (tid < 8) rW[b * 8 + tid] = r;
        float cur = 0.0f;
        float* rr = res + (b * 8 + h) * 128;
        #pragma unroll 1
        for (int f = 0; f < 64; ++f) {
            float av = __shfl(ampA, f);
            float c = fmaxf(cur + av * ha, 0.0f);
            if (tid < 8) rr[f] = c;
            cur = c * hd;
        }
        #pragma unroll 1
        for (int f = 0; f < 64; ++f) {
            float av = __shfl(ampB, f);
            float c = fmaxf(cur + av * ha, 0.0f);
            if (tid < 8) rr[64 + f] = c;
            cur = c * hd;
        }
    }
    __syncthreads();

    // --- radix-4 DIF stages ---
    r4_dif_stage<8192>(zz, tid);
    r4_dif_stage<2048>(zz, tid);
    r4_dif_stage<512>(zz, tid);
    r4_dif_stage<128>(zz, tid);
    r4_dif_stage<32>(zz, tid);

    // --- register radix-8 DIF (half=4,2,1), scalar vars, float2 LDS I/O ---
    #pragma unroll 1
    for (int s = 0; s < 2048 / NT; ++s) {
        int m = tid + s * NT;
        int a = MP(8 * m);      // = 9m, block of 8 contiguous float2
        float2 v0 = zz[a], v1 = zz[a + 1], v2 = zz[a + 2], v3 = zz[a + 3];
        float2 v4 = zz[a + 4], v5 = zz[a + 5], v6 = zz[a + 6], v7 = zz[a + 7];
        // half=4
        float t0r = v0.x + v4.x, t0i = v0.y + v4.y;
        float u0r = v0.x - v4.x, u0i = v0.y - v4.y;
        float t1r = v1.x + v5.x, t1i = v1.y + v5.y;
        float d1r = v1.x - v5.x, d1i = v1.y - v5.y;
        float u1r = RT2H * (d1r + d1i), u1i = RT2H * (d1i - d1r);   // *(c-ci)
        float t2r = v2.x + v6.x, t2i = v2.y + v6.y;
        float d2r = v2.x - v6.x, d2i = v2.y - v6.y;
        float u2r = d2i, u2i = -d2r;                                  // *(-i)
        float t3r = v3.x + v7.x, t3i = v3.y + v7.y;
        float d3r = v3.x - v7.x, d3i = v3.y - v7.y;
        float u3r = RT2H * (d3i - d3r), u3i = -RT2H * (d3r + d3i);  // *(-c-ci)
        // half=2
        float A0r = t0r + t2r, A0i = t0i + t2i;
        float A2r = t0r - t2r, A2i = t0i - t2i;
        float A1r = t1r + t3r, A1i = t1i + t3i;
        float e3r = t1r - t3r, e3i = t1i - t3i;
        float A3r = e3i, A3i = -e3r;                                  // *(-i)
        float B0r = u0r + u2r, B0i = u0i + u2i;
        float B2r = u0r - u2r, B2i = u0i - u2i;
        float B1r = u1r + u3r, B1i = u1i + u3i;
        float f3r = u1r - u3r, f3i = u1i - u3i;
        float B3r = f3i, B3i = -f3r;
        // half=1
        zz[a]     = make_float2(A0r + A1r, A0i + A1i);
        zz[a + 1] = make_float2(A0r - A1r, A0i - A1i);
        zz[a + 2] = make_float2(A2r + A3r, A2i + A3i);
        zz[a + 3] = make_float2(A2r - A3r, A2i - A3i);
        zz[a + 4] = make_float2(B0r + B1r, B0i + B1i);
        zz[a + 5] = make_float2(B0r - B1r, B0i - B1i);
        zz[a + 6] = make_float2(B2r + B3r, B2i + B3i);
        zz[a + 7] = make_float2(B2r - B3r, B2i - B3i);
    }
    __syncthreads();

    // --- pointwise untangle * H * retangle, bitrev domain ---
    // No /N_HARMONICS: reference broadcasts noise over harmonics then sums (R10 lesson).
    const float invM = 1.0f / (float)FFT_M;
    #pragma unroll 1
    for (int s = 0; s < 8192 / NT; ++s) {
        int jj = (tid + s * NT) << 1;       // even position
        if (jj == 0) {
            int p0 = MP(0);
            float2 z0 = zz[p0];
            float y = 0.5f * filt_at(filt, 0) * (z0.x + z0.y) * invM;
            zz[p0] = make_float2(y, y);
            int p1 = MP(1);                  // k=8192 self-pair at brev(8192)=1
            float H = filt_at(filt, 8192) * invM;
            float2 z1 = zz[p1];
            zz[p1] = make_float2(z1.x * H, z1.y * H);
        } else {
            int k = (int)(__brev((unsigned)jj) >> 18);     // k in [1,8192)
            int kq = FFT_M - k;
            int pk = MP(jj);
            int pq = MP((int)(__brev((unsigned)kq) >> 18));
            float2 zk = zz[pk], zq = zz[pq];
            float Er = 0.5f * (zk.x + zq.x), Ei = 0.5f * (zk.y - zq.y);
            float Or = 0.5f * (zk.y + zq.y), Oi = 0.5f * (zq.x - zk.x);
            float th = (float)k * (PI_F / (float)FFT_M);
            float s1, c1; __sincosf(th, &s1, &c1);
            float ts = -s1;
            float tOr = c1 * Or - ts * Oi;
            float tOi = c1 * Oi + ts * Or;
            float Hk = filt_at(filt, k);
            float Hq = filt_at(filt, kq);
            float Ykr = Hk * (Er + tOr), Yki = Hk * (Ei + tOi);
            float Cr  = Hq * (Er - tOr), Ci  = Hq * (Ei - tOi);
            float Ar = 0.5f * (Ykr + Cr), Ai = 0.5f * (Yki + Ci);
            float Br = 0.5f * (Ykr - Cr), Bi = 0.5f * (Yki - Ci);
            zz[pk] = make_float2((Ar + ts * Br - c1 * Bi) * invM,
                                 (Ai + c1 * Br + ts * Bi) * invM);
            zz[pq] = make_float2((Ar + c1 * Bi - ts * Br) * invM,
                                 (-Ai + c1 * Br + ts * Bi) * invM);
        }
    }
    __syncthreads();

    // --- register radix-8 DIT (half=1,2,4), scalar vars, float2 LDS I/O ---
    #pragma unroll 1
    for (int s = 0; s < 2048 / NT; ++s) {
        int m = tid + s * NT;
        int a = MP(8 * m);
        float2 v0 = zz[a], v1 = zz[a + 1], v2 = zz[a + 2], v3 = zz[a + 3];
        float2 v4 = zz[a + 4], v5 = zz[a + 5], v6 = zz[a + 6], v7 = zz[a + 7];
        // half=1
        float A0r = v0.x + v1.x, A0i = v0.y + v1.y;
        float A1r = v0.x - v1.x, A1i = v0.y - v1.y;
        float A2r = v2.x + v3.x, A2i = v2.y + v3.y;
        float A3r = v2.x - v3.x, A3i = v2.y - v3.y;
        float B0r = v4.x + v5.x, B0i = v4.y + v5.y;
        float B1r = v4.x - v5.x, B1i = v4.y - v5.y;
        float B2r = v6.x + v7.x, B2i = v6.y + v7.y;
        float B3r = v6.x - v7.x, B3i = v6.y - v7.y;
        // half=2 ; twiddle on odd: *(+i)
        float t0r = A0r + A2r, t0i = A0i + A2i;
        float t2r = A0r - A2r, t2i = A0i - A2i;
        float w3r = -A3i, w3i = A3r;
        float t1r = A1r + w3r, t1i = A1i + w3i;
        float t3r = A1r - w3r, t3i = A1i - w3i;
        float u0r = B0r + B2r, u0i = B0i + B2i;
        float u2r = B0r - B2r, u2i = B0i - B2i;
        float x3r = -B3i, x3i = B3r;
        float u1r = B1r + x3r, u1i = B1i + x3i;
        float u3r = B1r - x3r, u3i = B1i - x3i;
        // half=4 ; twiddles 1, c(1+i), +i, c(-1+i)
        float w1r = RT2H * (u1r - u1i), w1i = RT2H * (u1r + u1i);
        float w2r = -u2i,               w2i = u2r;
        float w5r = RT2H * (-u3r - u3i), w5i = RT2H * (u3r - u3i);
        zz[a]     = make_float2(t0r + u0r, t0i + u0i);
        zz[a + 4] = make_float2(t0r - u0r, t0i - u0i);
        zz[a + 1] = make_float2(t1r + w1r, t1i + w1i);
        zz[a + 5] = make_float2(t1r - w1r, t1i - w1i);
        zz[a + 2] = make_float2(t2r + w2r, t2i + w2i);
        zz[a + 6] = make_float2(t2r - w2r, t2i - w2i);
        zz[a + 3] = make_float2(t3r + w5r, t3i + w5i);
        zz[a + 7] = make_float2(t3r - w5r, t3i - w5i);
    }
    __syncthreads();

    // --- radix-4 DIT stages ---
    r4_dit_stage<32>(zz, tid);
    r4_dit_stage<128>(zz, tid);
    r4_dit_stage<512>(zz, tid);
    r4_dit_stage<2048>(zz, tid);
    r4_dit_stage<8192>(zz, tid);

    // --- fused final r2 DIT (half=8192) + store ---
    float2* oz = (float2*)(noise_out + (size_t)b * N_SAMPLES);
    #pragma unroll 1
    for (int s = 0; s < 8192 / NT; ++s) {
        int j = tid + s * NT;
        float2 u = zz[MP(j)];
        float2 x = zz[MP(j + 8192)];
        float s1, c1; __sincosf((PI_F / 8192.0f) * (float)j, &s1, &c1);
        float wr = x.x * c1 - x.y * s1, wi = x.x * s1 + x.y * c1;
        oz[j] = make_float2(u.x + wr, u.y + wi);
        oz[j + 8192] = make_float2(u.x - wr, u.y - wi);
    }
}

// ---------------- K2: gate noise, add harmonic bank, sum 8 events ----------------
// Chebyshev: r_h = h*r_1, so sin((n+1)*r_h) = U-recurrence from one sincos.
__global__ __launch_bounds__(256) void assemble_kernel(
    const float* __restrict__ packed, const float* __restrict__ rW,
    const float* __restrict__ res, const float* __restrict__ noise_out,
    const float* __restrict__ oamp, float* __restrict__ out)
{
    const int g = blockIdx.y;
    const int chunk = blockIdx.x;
    const int tid = threadIdx.x;
    const int n = chunk * 256 + tid;
    const int fb = chunk - 1;

    __shared__ float s_res[8][8][3];
    __shared__ float s_ampf[8][3];
    __shared__ float s_r[8][8];
    if (tid < 192) {
        int e = tid / 24, rem = tid % 24, h = rem / 3, j = rem % 3;
        int f = min(max(fb + j, 0), 127);
        s_res[e][h][j] = res[((g * 8 + e) * 8 + h) * 128 + f];
    }
    if (tid < 24) {
        int e = tid / 3, j = tid % 3;
        int f = min(max(fb + j, 0), 127);
        s_ampf[e][j] = packed[(g * 8 + e) * PCK_STRIDE + 256 + f] * 2.0f - 1.0f;
    }
    if (tid >= 192 && tid < 256) {
        int u = tid - 192;
        s_r[u / 8][u % 8] = rW[g * 64 + u];
    }
    __syncthreads();

    float coords = ((float)n + 0.5f) * (1.0f / 256.0f) - 0.5f;
    coords = fminf(fmaxf(coords, 0.0f), 127.0f);
    int i0 = (int)floorf(coords);
    float w = coords - (float)i0;
    int j0 = i0 - fb;
    float osc50 = oamp[0];
    float pn = (float)(n + 1);
    float wm = 1.0f - w;

    float acc = 0.0f;
    #pragma unroll
    for (int e = 0; e < 8; ++e) {
        int b = g * 8 + e;
        float nv = noise_out[(size_t)b * N_SAMPLES + n];
        float av = s_ampf[e][j0] * wm + s_ampf[e][j0 + 1] * w;
        float gate = (av >= 0.0f) ? av : 0.2f * av;
        acc += nv * gate;
        float sn, cn; __sincosf(pn * s_r[e][0], &sn, &cn);
        float c2 = 2.0f * cn;
        float shm1 = 0.0f, sh = sn;
        #pragma unroll
        for (int h = 0; h < 8; ++h) {
            float rsv = s_res[e][h][j0] * wm + s_res[e][h][j0 + 1] * w;
            float sv = (s_r[e][h] != 0.0f) ? sh : 0.0f;
            acc += rsv * osc50 * sv;
            float nx = c2 * sh - shm1;
            shm1 = sh; sh = nx;
        }
    }
    out[(size_t)g * N_SAMPLES + n] = acc;
}

extern "C" void kernel_launch(void* const* d_in, const int* in_sizes, int n_in,
                              void* d_out, int out_size, void* d_ws, size_t ws_size,
                              hipStream_t stream) {
    const float* packed = (const float*)d_in[0];
    const float* freqs  = (const float*)d_in[1];
    const float* gamp   = (const float*)d_in[2];
    const float* oamp   = (const float*)d_in[3];
    const float* noise  = (const float*)d_in[4];
    float* out = (float*)d_out;

    float* ws = (float*)d_ws;
    float* noise_out = ws;
    float* res = ws + (size_t)B_EVENTS * N_SAMPLES;
    float* rW  = res + B_EVENTS * 8 * 128;

    fft_filter_kernel<<<B_EVENTS, NT, LDS_BYTES, stream>>>(
        noise, packed, gamp, noise_out, freqs, rW, res);
    assemble_kernel<<<dim3(N_SAMPLES / 256, N_GROUPS), 256, 0, stream>>>(
        packed, rW, res, noise_out, oamp, out);
}